// Round 3
// baseline (280.675 us; speedup 1.0000x reference)
//
#include <hip/hip_runtime.h>
#include <hip/hip_bf16.h>
#include <stdint.h>

// Problem constants (B,T,C) = (4,4096,1024)
#define TT 4096
#define BB 4
#define CC 1024
#define MM (BB * TT)          // 16384 rows
#define NCHUNK 128            // scan chunks along T
#define CHUNK_T (TT / NCHUNK) // 32 steps per chunk
#define NCHAIN (BB * CC)      // 4096 independent scan chains

typedef float f32x4 __attribute__((ext_vector_type(4)));
typedef __bf16 bf16x8 __attribute__((ext_vector_type(8)));

__device__ __forceinline__ float b2f(ushort u) {
  union { float f; uint32_t v; } x; x.v = ((uint32_t)u) << 16; return x.f;
}
__device__ __forceinline__ ushort f2b(float f) { // RNE fp32->bf16
  union { float f; uint32_t u; } x; x.f = f;
  uint32_t r = x.u + 0x7fffu + ((x.u >> 16) & 1u);
  return (ushort)(r >> 16);
}

// async global->LDS, 16B per lane. LDS dest must be uniform-base + lane*16.
__device__ __forceinline__ void async_copy16(const ushort* g, ushort* l) {
  __builtin_amdgcn_global_load_lds(
      (__attribute__((address_space(1))) void*)(g),
      (__attribute__((address_space(3))) void*)(l), 16, 0, 0);
}

// One kernel converts x, Wf, Wg, Wp to bf16. Sizes in float4 units:
// x: 4194304, each W: 262144. Total 4980736 = 19456 * 256 exactly.
__global__ __launch_bounds__(256) void cvt_all(const float* __restrict__ x,
                                               const float* __restrict__ wf,
                                               const float* __restrict__ wg,
                                               const float* __restrict__ wp,
                                               ushort* __restrict__ xb,
                                               ushort* __restrict__ wcat,
                                               ushort* __restrict__ wpb) {
  const int i = blockIdx.x * 256 + threadIdx.x;
  const float* s; ushort* d; int off;
  if (i < 4194304)            { s = x;  d = xb;              off = i; }
  else if (i < 4456448)       { s = wf; d = wcat;            off = i - 4194304; }
  else if (i < 4718592)       { s = wg; d = wcat + 1048576;  off = i - 4456448; }
  else                        { s = wp; d = wpb;             off = i - 4718592; }
  float4 v = ((const float4*)s)[off];
  ushort4 o;
  o.x = f2b(v.x); o.y = f2b(v.y); o.z = f2b(v.z); o.w = f2b(v.w);
  ((ushort4*)d)[off] = o;
}

// ===========================================================================
// ROUND-9: m201-style 8-phase schedule (the measured escape from the 2-phase
// ~830 TF plateau; m201 = 1563 TF on this exact 256^2/512thr/128KiB geometry).
//
// Geometry: BM=BN=256, BK=64, 8 waves (2M x 4N), wave tile 128x64.
// K staging in K-HALF pieces (256 rows x 32 k = 16 KB): ring of 4 slots per
// matrix, slot(t,s) = (2t+s)&3. Stage order for tile t+1 during tile t's 4
// phases: P0->As0, P1->Bs0, P2->As1, P3->Bs1 (2 gload_lds/wave per piece).
//
// Phase p = (k-half s, i-half ih):
//   ds_read: 4 A frags (+4 B frags when ih==0; B regs reused at ih==1)
//   stage 1 piece of tile t+1
//   s_barrier; s_waitcnt lgkmcnt(0); sched_barrier(0)        [rule #18]
//   setprio(1); 16x mfma_16x16x32_bf16; setprio(0)           [T5: pays at 8ph]
//   [vmcnt(4) at end of P1 and P3 only -- never drains in main loop]
//   s_barrier; sched_barrier(0)
//
// vmcnt audit (per wave, symmetric): at end-P1(t): outstanding =
// {As1(t),Bs1(t) (issued P2,P3 of t-1)} + {As0(t+1),Bs0(t+1) (P0,P1 of t)}
// = 8; vmcnt(4) confirms As1,Bs1(t) -- first read at P2(t), ~2.5 phases of
// slack since issue. Symmetric at end-P3. WAR: a slot's last ds_read is
// lgkm-consumed before its phase's MFMA, >=2 phase-barriers before that
// slot's next gload_lds overwrite is issued.
//
// LDS swizzle: piece rows are 64 B (4 octets) -- byte-identical geometry to
// the R7/R8 pattern that measured 0 bank conflicts: octet o of row r at slot
// o ^ ((r>>1)&3); staging pre-swizzles the GLOBAL octet (involution, rule
// #21). Operand-swapped MFMA (R3): n on reg axis -> packed 4-wide stores.
// Accumulation k-order unchanged (tiles ascending, s0 then s1) -> numerics
// identical to R8.
// ===========================================================================

#define RDA(sl, ih)                                                       \
  _Pragma("unroll") for (int i_ = 0; i_ < 4; ++i_)                        \
      af[i_] = *(const bf16x8*)(rA + (sl) * 8192 + (ih) * 2048 + i_ * 512);

#define RDB(sl)                                                           \
  _Pragma("unroll") for (int j_ = 0; j_ < 4; ++j_)                        \
      bfr[j_] = *(const bf16x8*)(rB + (sl) * 8192 + j_ * 512);

#define MFMA16(ih)                                                        \
  __builtin_amdgcn_s_setprio(1);                                          \
  _Pragma("unroll") for (int i_ = 0; i_ < 4; ++i_)                        \
  _Pragma("unroll") for (int j_ = 0; j_ < 4; ++j_)                        \
      acc[(ih) * 4 + i_][j_] = __builtin_amdgcn_mfma_f32_16x16x32_bf16(   \
          bfr[j_], af[i_], acc[(ih) * 4 + i_][j_], 0, 0, 0);              \
  __builtin_amdgcn_s_setprio(0)

#define MIDBAR()                                                          \
  __builtin_amdgcn_s_barrier();                                           \
  asm volatile("s_waitcnt lgkmcnt(0)" ::: "memory");                      \
  __builtin_amdgcn_sched_barrier(0)

#define ENDBAR()                                                          \
  __builtin_amdgcn_s_barrier();                                           \
  __builtin_amdgcn_sched_barrier(0)

#define CK4() asm volatile("s_waitcnt vmcnt(4)" ::: "memory")
#define CK0() asm volatile("s_waitcnt vmcnt(0)" ::: "memory")

// One K-tile (BK=64) = 4 phases; stages the 4 pieces of the NEXT tile.
#define TILE(S0, S1, NS0, NS1, KN)                                        \
  RDA(S0, 0); RDB(S0); stageA(NS0, (KN));      MIDBAR(); MFMA16(0);        ENDBAR(); \
  RDA(S0, 1);          stageB(NS0, (KN));      MIDBAR(); MFMA16(1); CK4(); ENDBAR(); \
  RDA(S1, 0); RDB(S1); stageA(NS1, (KN) + 32); MIDBAR(); MFMA16(0);        ENDBAR(); \
  RDA(S1, 1);          stageB(NS1, (KN) + 32); MIDBAR(); MFMA16(1); CK4(); ENDBAR();

template <int MODE>
__global__ __launch_bounds__(512, 2) void gemm_bt(const ushort* __restrict__ A,
                                                  const ushort* __restrict__ Bw,
                                                  float* __restrict__ outF,
                                                  ushort* __restrict__ outB, int N) {
  constexpr int K = CC; // 1024 -> 16 K-tiles of 64 (32 K-half pieces)
  __shared__ __align__(16) ushort sA[4 * 256 * 32]; // 4 x 16 KB ring = 64 KB
  __shared__ __align__(16) ushort sB[4 * 256 * 32]; // 64 KB

  const int tid = threadIdx.x;
  const int lane = tid & 63;
  const int w = tid >> 6;  // 0..7
  const int wm = w >> 2;   // 0..1: 128-row M half
  const int wn = w & 3;    // 0..3: 64-col N quarter

  // XCD-aware bijective swizzle (nwg = 512 or 256, both % 8 == 0)
  const int nbx = N >> 8;
  const int cpx = (int)gridDim.x >> 3;
  const int bid = blockIdx.x;
  const int wg = (bid & 7) * cpx + (bid >> 3);
  const long n0 = (long)(wg % nbx) << 8;
  const long m0 = (long)(wg / nbx) << 8;

  // ---- staging: piece = 256 rows x 64 B. Wave w covers rows w*16..+15 (hb0)
  // and 128+w*16..+15 (hb1), one gload_lds (1 KB) each. lane -> row lane>>2,
  // LDS octet lane&3; global octet pre-swizzled (lane&3)^((lane>>3)&3).
  const int srow = lane >> 2;
  const int goct = (lane & 3) ^ ((lane >> 3) & 3);
  const ushort* gA0 = A + (m0 + w * 16 + srow) * K + goct * 8;
  const ushort* gB0 = Bw + (n0 + w * 16 + srow) * K + goct * 8;
  const ushort* gA1 = gA0 + 128 * (long)K;
  const ushort* gB1 = gB0 + 128 * (long)K;
  ushort* dA0 = &sA[w * 512 + lane * 8];
  ushort* dA1 = dA0 + 4096; // rows +128 within piece
  ushort* dB0 = &sB[w * 512 + lane * 8];
  ushort* dB1 = dB0 + 4096;

  auto stageA = [&](int slot, int koff) {
    async_copy16(gA0 + koff, dA0 + slot * 8192);
    async_copy16(gA1 + koff, dA1 + slot * 8192);
  };
  auto stageB = [&](int slot, int koff) {
    async_copy16(gB0 + koff, dB0 + slot * 8192);
    async_copy16(gB1 + koff, dB1 + slot * 8192);
  };

  // ---- fragment reads: row r, octet slot kq ^ ((r>>1)&3)  (R7 0-conflict)
  const int rlo = lane & 15;
  const int kq = lane >> 4;
  const int oslot = kq ^ ((rlo >> 1) & 3);
  const ushort* rA = &sA[(wm * 128 + rlo) * 32 + oslot * 8]; // +sl*8192+ih*2048+i*512
  const ushort* rB = &sB[(wn * 64 + rlo) * 32 + oslot * 8];  // +sl*8192+j*512

  f32x4 acc[8][4];
#pragma unroll
  for (int i = 0; i < 8; ++i)
#pragma unroll
    for (int j = 0; j < 4; ++j) acc[i][j] = (f32x4){0.f, 0.f, 0.f, 0.f};

  bf16x8 af[4], bfr[4];

  // prologue: stage tile 0's 4 pieces; confirm As0,Bs0 (leave As1,Bs1 flying)
  stageA(0, 0);
  stageB(0, 0);
  stageA(1, 32);
  stageB(1, 32);
  CK4();
  ENDBAR();

  // main loop: tiles 0..13 (2 per iter; slot pattern period 2 -> constants)
  for (int t2 = 0; t2 < 7; ++t2) {
    const int kn = t2 * 128 + 64; // stage koff for tile 2*t2+1
    TILE(0, 1, 2, 3, kn);         // even tile: reads slots 0,1; stages 2,3
    TILE(2, 3, 0, 1, kn + 64);    // odd tile:  reads slots 2,3; stages 0,1
  }
  // tile 14 (even): stages tile 15 (slots 2,3; koff 960/992)
  TILE(0, 1, 2, 3, 960);
  // tile 15 (odd, slots 2,3): no stages; drain only here
  RDA(2, 0); RDB(2); MIDBAR(); MFMA16(0); ENDBAR();
  RDA(2, 1);         MIDBAR(); MFMA16(1); CK0(); ENDBAR();
  RDA(3, 0); RDB(3); MIDBAR(); MFMA16(0); ENDBAR();
  RDA(3, 1);         MIDBAR(); MFMA16(1);

  // Swapped C/D mapping (R3-verified): m = lane&15 axis, n = (lane>>4)*4 + reg.
  const int mloc = lane & 15;
  const int nq = (lane >> 4) * 4;
#pragma unroll
  for (int i = 0; i < 8; ++i) {
    const long m = m0 + wm * 128 + i * 16 + mloc;
#pragma unroll
    for (int j = 0; j < 4; ++j) {
      const long nb = n0 + wn * 64 + j * 16 + nq; // 4 consecutive n
      const f32x4 v = acc[i][j];
      if (MODE == 0) {
        *(f32x4*)(outF + m * N + nb) = v;
      } else {
        float act[4];
        if (n0 < CC) { // sigmoid region (block-uniform; 256 | 1024)
#pragma unroll
          for (int r = 0; r < 4; ++r)
            act[r] = __builtin_amdgcn_rcpf(1.f + __expf(-v[r]));
        } else {       // tanh = 1 - 2/(exp(2v)+1)
#pragma unroll
          for (int r = 0; r < 4; ++r)
            act[r] = fmaf(-2.f, __builtin_amdgcn_rcpf(1.f + __expf(2.f * v[r])), 1.f);
        }
        ushort4 o;
        o.x = f2b(act[0]); o.y = f2b(act[1]); o.z = f2b(act[2]); o.w = f2b(act[3]);
        *(ushort4*)(outB + m * (long)N + nb) = o;
      }
    }
  }
}

// ===== Scan: R1-style 3-pass (cheapest measured), vectorized 4 chains/thread =====
// P layout: [m=b*T+t][0..1023]=f (bf16), [1024..2047]=g (bf16)
__global__ __launch_bounds__(256) void scan_pass1(const ushort* __restrict__ P,
                                                  float* __restrict__ cA,
                                                  float* __restrict__ cB) {
  const int pc = blockIdx.x * 256 + threadIdx.x; // chain quad 0..1023
  const int chunk = blockIdx.y;
  const int b = pc >> 8, c4 = (pc & 255) * 4;
  const ushort4* p =
      (const ushort4*)(P + (size_t)(b * TT + chunk * CHUNK_T) * (2 * CC) + c4);
  float A[4] = {1.f, 1.f, 1.f, 1.f};
  float h[4] = {0.f, 0.f, 0.f, 0.f};
#pragma unroll 4
  for (int i = 0; i < CHUNK_T; ++i) {
    const ushort4 fu = p[0];
    const ushort4 gu = p[CC / 4];
    p += 2 * CC / 4;
    const float f[4] = {b2f(fu.x), b2f(fu.y), b2f(fu.z), b2f(fu.w)};
    const float g[4] = {b2f(gu.x), b2f(gu.y), b2f(gu.z), b2f(gu.w)};
#pragma unroll
    for (int r = 0; r < 4; ++r) {
      A[r] *= f[r];
      h[r] = fmaf(f[r], h[r], (1.f - f[r]) * g[r]);
    }
  }
  const int ci = chunk * NCHAIN + b * CC + c4;
  *(f32x4*)(cA + ci) = (f32x4){A[0], A[1], A[2], A[3]};
  *(f32x4*)(cB + ci) = (f32x4){h[0], h[1], h[2], h[3]};
}

__global__ __launch_bounds__(256) void scan_pass2(const float* __restrict__ cA,
                                                  const float* __restrict__ cB,
                                                  float* __restrict__ hinit) {
  const int chain = blockIdx.x * 256 + threadIdx.x; // 0..4095
  float h = 0.f;
  for (int j = 0; j < NCHUNK; ++j) {
    hinit[j * NCHAIN + chain] = h; // exclusive carry
    h = fmaf(cA[j * NCHAIN + chain], h, cB[j * NCHAIN + chain]);
  }
}

__global__ __launch_bounds__(256) void scan_pass3(const ushort* __restrict__ P,
                                                  const float* __restrict__ hinit,
                                                  ushort* __restrict__ H) {
  const int pc = blockIdx.x * 256 + threadIdx.x;
  const int chunk = blockIdx.y;
  const int b = pc >> 8, c4 = (pc & 255) * 4;
  f32x4 hv = *(const f32x4*)(hinit + chunk * NCHAIN + b * CC + c4);
  float h[4] = {hv[0], hv[1], hv[2], hv[3]};
  const ushort4* p =
      (const ushort4*)(P + (size_t)(b * TT + chunk * CHUNK_T) * (2 * CC) + c4);
  ushort4* hp = (ushort4*)(H + (size_t)(b * TT + chunk * CHUNK_T) * CC + c4);
#pragma unroll 4
  for (int i = 0; i < CHUNK_T; ++i) {
    const ushort4 fu = p[0];
    const ushort4 gu = p[CC / 4];
    p += 2 * CC / 4;
    const float f[4] = {b2f(fu.x), b2f(fu.y), b2f(fu.z), b2f(fu.w)};
    const float g[4] = {b2f(gu.x), b2f(gu.y), b2f(gu.z), b2f(gu.w)};
    ushort4 o;
#pragma unroll
    for (int r = 0; r < 4; ++r)
      h[r] = fmaf(f[r], h[r], (1.f - f[r]) * g[r]);
    o.x = f2b(h[0]); o.y = f2b(h[1]); o.z = f2b(h[2]); o.w = f2b(h[3]);
    *hp = o;
    hp += CC / 4;
  }
}

extern "C" void kernel_launch(void* const* d_in, const int* in_sizes, int n_in,
                              void* d_out, int out_size, void* d_ws, size_t ws_size,
                              hipStream_t stream) {
  const float* x  = (const float*)d_in[0];
  const float* Wf = (const float*)d_in[1];
  const float* Wg = (const float*)d_in[2];
  const float* Wp = (const float*)d_in[3];

  // workspace layout (bytes); H aliases xb (xb dead after gates GEMM).
  // cA/cB overlay Wcat (dead after gates GEMM; stream-ordered).
  char* ws = (char*)d_ws;
  ushort* xb   = (ushort*)(ws);                                  // 33554432 B
  ushort* Hb   = xb;                                             // alias
  ushort* Wcat = (ushort*)(ws + 33554432);                       //  4194304 B (Wf||Wg)
  ushort* Wpb  = (ushort*)(ws + 33554432 + 4194304);             //  2097152 B
  ushort* P    = (ushort*)(ws + 33554432 + 4194304 + 2097152);   // 67108864 B (f||g bf16)
  char* tail   = ws + 33554432 + 4194304 + 2097152 + 67108864;
  float* cA    = (float*)Wcat;                                   // 2 MiB overlay
  float* cB    = (float*)(((char*)Wcat) + 2097152);              // 2 MiB overlay
  float* hinit = (float*)(tail);                                 // 2 MiB (128*4096*4)
  (void)ws_size; (void)in_sizes; (void)n_in; (void)out_size;

  // 1) all fp32 -> bf16 conversions in one launch
  cvt_all<<<19456, 256, 0, stream>>>(x, Wf, Wg, Wp, xb, Wcat, Wpb);

  // 2) gates GEMM: [16384 x 2048] = xb @ Wcat^T, fused sigmoid/tanh -> P (bf16)
  gemm_bt<1><<<512, 512, 0, stream>>>(xb, Wcat, nullptr, P, 2 * CC);

  // 3) chunked scan: 3-pass (per-chunk compose, carry scan, fixup)
  dim3 gs(NCHAIN / 4 / 256, NCHUNK);
  scan_pass1<<<gs, 256, 0, stream>>>(P, cA, cB);
  scan_pass2<<<NCHAIN / 256, 256, 0, stream>>>(cA, cB, hinit);
  scan_pass3<<<gs, 256, 0, stream>>>(P, hinit, Hb);

  // 4) projection GEMM: out = H @ Wp^T (fp32), 256x256 tiles -> 256 blocks
  gemm_bt<0><<<256, 512, 0, stream>>>(Hb, Wpb, (float*)d_out, nullptr, CC);
}

// Round 4
// 269.871 us; speedup vs baseline: 1.0400x; 1.0400x over previous
//
#include <hip/hip_runtime.h>
#include <hip/hip_bf16.h>
#include <stdint.h>

// Problem constants (B,T,C) = (4,4096,1024)
#define TT 4096
#define BB 4
#define CC 1024
#define MM (BB * TT)          // 16384 rows
#define NCHUNK 64             // scan chunks along T
#define CHUNK_T (TT / NCHUNK) // 64 steps per chunk
#define NCHAIN (BB * CC)      // 4096 independent scan chains

typedef float f32x4 __attribute__((ext_vector_type(4)));
typedef __bf16 bf16x8 __attribute__((ext_vector_type(8)));
typedef ushort us8 __attribute__((ext_vector_type(8)));

__device__ __forceinline__ float b2f(ushort u) {
  union { float f; uint32_t v; } x; x.v = ((uint32_t)u) << 16; return x.f;
}
__device__ __forceinline__ ushort f2b(float f) { // RNE fp32->bf16
  union { float f; uint32_t u; } x; x.f = f;
  uint32_t r = x.u + 0x7fffu + ((x.u >> 16) & 1u);
  return (ushort)(r >> 16);
}

// async global->LDS, 16B per lane. LDS dest must be uniform-base + lane*16.
__device__ __forceinline__ void async_copy16(const ushort* g, ushort* l) {
  __builtin_amdgcn_global_load_lds(
      (__attribute__((address_space(1))) void*)(g),
      (__attribute__((address_space(3))) void*)(l), 16, 0, 0);
}

// One kernel converts x, Wf, Wg, Wp to bf16. Sizes in float4 units:
// x: 4194304, each W: 262144. Total 4980736 = 19456 * 256 exactly.
// ROUND-10: Wcat rows INTERLEAVED: row 2c = Wf[c], row 2c+1 = Wg[c], so the
// gates GEMM n-axis carries (f,g) channel pairs -> epilogue chunk-compose.
__global__ __launch_bounds__(256) void cvt_all(const float* __restrict__ x,
                                               const float* __restrict__ wf,
                                               const float* __restrict__ wg,
                                               const float* __restrict__ wp,
                                               ushort* __restrict__ xb,
                                               ushort* __restrict__ wcat,
                                               ushort* __restrict__ wpb) {
  const int i = blockIdx.x * 256 + threadIdx.x;
  const float* s; ushort* d; int off, dst;
  if (i < 4194304) {
    s = x; d = xb; off = i; dst = i;
  } else if (i < 4456448) {
    s = wf; d = wcat; off = i - 4194304;
    dst = ((off >> 8) << 9) + (off & 255);        // row c -> row 2c
  } else if (i < 4718592) {
    s = wg; d = wcat; off = i - 4456448;
    dst = ((off >> 8) << 9) + 256 + (off & 255);  // row c -> row 2c+1
  } else {
    s = wp; d = wpb; off = i - 4718592; dst = off;
  }
  float4 v = ((const float4*)s)[off];
  ushort4 o;
  o.x = f2b(v.x); o.y = f2b(v.y); o.z = f2b(v.z); o.w = f2b(v.w);
  ((ushort4*)d)[dst] = o;
}

// ===========================================================================
// GEMM core unchanged from R9 (8-phase, 4-slot ring, counted vmcnt; 82.5 us,
// absmax-proven). R10 changes are EPILOGUE-ONLY (MODE 1):
//  - activation parity per accumulator reg (n even -> sigmoid f, odd -> tanh g)
//  - fused chunk composition: per chunk of 64 t (4 sixteen-lane windows),
//    ordered shfl_xor compose tree over mloc, serial compose over windows,
//    lane mloc==0 writes (A,B) to cA2/cB2 [chain][64] chain-major.
//    Composition uses the bf16-ROUNDED f,g (same values pass3 reads from P)
//    -> numerics match the deleted pass1 within fp associativity.
// ===========================================================================

#define RDA(sl, ih)                                                       \
  _Pragma("unroll") for (int i_ = 0; i_ < 4; ++i_)                        \
      af[i_] = *(const bf16x8*)(rA + (sl) * 8192 + (ih) * 2048 + i_ * 512);

#define RDB(sl)                                                           \
  _Pragma("unroll") for (int j_ = 0; j_ < 4; ++j_)                        \
      bfr[j_] = *(const bf16x8*)(rB + (sl) * 8192 + j_ * 512);

#define MFMA16(ih)                                                        \
  __builtin_amdgcn_s_setprio(1);                                          \
  _Pragma("unroll") for (int i_ = 0; i_ < 4; ++i_)                        \
  _Pragma("unroll") for (int j_ = 0; j_ < 4; ++j_)                        \
      acc[(ih) * 4 + i_][j_] = __builtin_amdgcn_mfma_f32_16x16x32_bf16(   \
          bfr[j_], af[i_], acc[(ih) * 4 + i_][j_], 0, 0, 0);              \
  __builtin_amdgcn_s_setprio(0)

#define MIDBAR()                                                          \
  __builtin_amdgcn_s_barrier();                                           \
  asm volatile("s_waitcnt lgkmcnt(0)" ::: "memory");                      \
  __builtin_amdgcn_sched_barrier(0)

#define ENDBAR()                                                          \
  __builtin_amdgcn_s_barrier();                                           \
  __builtin_amdgcn_sched_barrier(0)

#define CK4() asm volatile("s_waitcnt vmcnt(4)" ::: "memory")
#define CK0() asm volatile("s_waitcnt vmcnt(0)" ::: "memory")

// One K-tile (BK=64) = 4 phases; stages the 4 pieces of the NEXT tile.
#define TILE(S0, S1, NS0, NS1, KN)                                        \
  RDA(S0, 0); RDB(S0); stageA(NS0, (KN));      MIDBAR(); MFMA16(0);        ENDBAR(); \
  RDA(S0, 1);          stageB(NS0, (KN));      MIDBAR(); MFMA16(1); CK4(); ENDBAR(); \
  RDA(S1, 0); RDB(S1); stageA(NS1, (KN) + 32); MIDBAR(); MFMA16(0);        ENDBAR(); \
  RDA(S1, 1);          stageB(NS1, (KN) + 32); MIDBAR(); MFMA16(1); CK4(); ENDBAR();

// Ordered 16-lane compose tree over the mloc axis (t = ...*16 + mloc).
// compose(L,R): A' = A_R*A_L ; B' = A_R*B_L + B_R. Both lanes of each pair
// end with the pair-window result; after 4 steps all 16 lanes hold the
// window compose in t-order.
#define BFLY16(Av, Bv)                                                    \
  _Pragma("unroll") for (int m_ = 1; m_ < 16; m_ <<= 1) {                 \
    float Ao_ = __shfl_xor(Av, m_);                                       \
    float Bo_ = __shfl_xor(Bv, m_);                                       \
    Bv = ((lane & m_) == 0) ? fmaf(Ao_, Bv, Bo_) : fmaf(Av, Bo_, Bv);     \
    Av = Ao_ * Av;                                                        \
  }

template <int MODE>
__global__ __launch_bounds__(512, 2) void gemm_bt(const ushort* __restrict__ A,
                                                  const ushort* __restrict__ Bw,
                                                  float* __restrict__ outF,
                                                  ushort* __restrict__ outB,
                                                  float* __restrict__ cA2,
                                                  float* __restrict__ cB2, int N) {
  constexpr int K = CC; // 1024 -> 16 K-tiles of 64 (32 K-half pieces)
  __shared__ __align__(16) ushort sA[4 * 256 * 32]; // 4 x 16 KB ring = 64 KB
  __shared__ __align__(16) ushort sB[4 * 256 * 32]; // 64 KB

  const int tid = threadIdx.x;
  const int lane = tid & 63;
  const int w = tid >> 6;  // 0..7
  const int wm = w >> 2;   // 0..1: 128-row M half
  const int wn = w & 3;    // 0..3: 64-col N quarter

  // XCD-aware bijective swizzle (nwg = 512 or 256, both % 8 == 0)
  const int nbx = N >> 8;
  const int cpx = (int)gridDim.x >> 3;
  const int bid = blockIdx.x;
  const int wg = (bid & 7) * cpx + (bid >> 3);
  const long n0 = (long)(wg % nbx) << 8;
  const long m0 = (long)(wg / nbx) << 8;

  // ---- staging: piece = 256 rows x 64 B. Wave w covers rows w*16..+15 (hb0)
  // and 128+w*16..+15 (hb1), one gload_lds (1 KB) each. lane -> row lane>>2,
  // LDS octet lane&3; global octet pre-swizzled (lane&3)^((lane>>3)&3).
  const int srow = lane >> 2;
  const int goct = (lane & 3) ^ ((lane >> 3) & 3);
  const ushort* gA0 = A + (m0 + w * 16 + srow) * K + goct * 8;
  const ushort* gB0 = Bw + (n0 + w * 16 + srow) * K + goct * 8;
  const ushort* gA1 = gA0 + 128 * (long)K;
  const ushort* gB1 = gB0 + 128 * (long)K;
  ushort* dA0 = &sA[w * 512 + lane * 8];
  ushort* dA1 = dA0 + 4096; // rows +128 within piece
  ushort* dB0 = &sB[w * 512 + lane * 8];
  ushort* dB1 = dB0 + 4096;

  auto stageA = [&](int slot, int koff) {
    async_copy16(gA0 + koff, dA0 + slot * 8192);
    async_copy16(gA1 + koff, dA1 + slot * 8192);
  };
  auto stageB = [&](int slot, int koff) {
    async_copy16(gB0 + koff, dB0 + slot * 8192);
    async_copy16(gB1 + koff, dB1 + slot * 8192);
  };

  // ---- fragment reads: row r, octet slot kq ^ ((r>>1)&3)  (R7 0-conflict)
  const int rlo = lane & 15;
  const int kq = lane >> 4;
  const int oslot = kq ^ ((rlo >> 1) & 3);
  const ushort* rA = &sA[(wm * 128 + rlo) * 32 + oslot * 8]; // +sl*8192+ih*2048+i*512
  const ushort* rB = &sB[(wn * 64 + rlo) * 32 + oslot * 8];  // +sl*8192+j*512

  f32x4 acc[8][4];
#pragma unroll
  for (int i = 0; i < 8; ++i)
#pragma unroll
    for (int j = 0; j < 4; ++j) acc[i][j] = (f32x4){0.f, 0.f, 0.f, 0.f};

  bf16x8 af[4], bfr[4];

  // prologue: stage tile 0's 4 pieces; confirm As0,Bs0 (leave As1,Bs1 flying)
  stageA(0, 0);
  stageB(0, 0);
  stageA(1, 32);
  stageB(1, 32);
  CK4();
  ENDBAR();

  // main loop: tiles 0..13 (2 per iter; slot pattern period 2 -> constants)
  for (int t2 = 0; t2 < 7; ++t2) {
    const int kn = t2 * 128 + 64; // stage koff for tile 2*t2+1
    TILE(0, 1, 2, 3, kn);         // even tile: reads slots 0,1; stages 2,3
    TILE(2, 3, 0, 1, kn + 64);    // odd tile:  reads slots 2,3; stages 0,1
  }
  // tile 14 (even): stages tile 15 (slots 2,3; koff 960/992)
  TILE(0, 1, 2, 3, 960);
  // tile 15 (odd, slots 2,3): no stages; drain only here
  RDA(2, 0); RDB(2); MIDBAR(); MFMA16(0); ENDBAR();
  RDA(2, 1);         MIDBAR(); MFMA16(1); CK0(); ENDBAR();
  RDA(3, 0); RDB(3); MIDBAR(); MFMA16(0); ENDBAR();
  RDA(3, 1);         MIDBAR(); MFMA16(1);

  // Swapped C/D mapping (R3-verified): m = lane&15 axis, n = (lane>>4)*4 + reg.
  const int mloc = lane & 15;
  const int nq = (lane >> 4) * 4;

  if (MODE == 0) {
#pragma unroll
    for (int i = 0; i < 8; ++i) {
      const long m = m0 + wm * 128 + i * 16 + mloc;
#pragma unroll
      for (int j = 0; j < 4; ++j) {
        const long nb = n0 + wn * 64 + j * 16 + nq;
        *(f32x4*)(outF + m * N + nb) = acc[i][j];
      }
    }
  } else {
    // ---- fused activation + P store + chunk composition ----
    const int kq4 = lane >> 4;
    const long bIdx = m0 >> 12;                     // batch
    const int t0 = (int)(m0 & 4095) + wm * 128;     // wm-half t base
    const long chb = (n0 >> 1) + wn * 32;           // channel base of this wave
#pragma unroll
    for (int cp = 0; cp < 2; ++cp) {                // chunk (64 t) in wm-half
      float CA[4][2], CB[4][2];                     // [j][s] running compose
#pragma unroll
      for (int hh = 0; hh < 4; ++hh) {              // 16-t windows, t-order
        const int i = cp * 4 + hh;
        const long m = m0 + wm * 128 + i * 16 + mloc;
#pragma unroll
        for (int j = 0; j < 4; ++j) {
          const long nb = n0 + wn * 64 + j * 16 + nq;
          const f32x4 v = acc[i][j];
          // parity activation: even n = f (sigmoid), odd n = g (tanh)
          float act0 = __builtin_amdgcn_rcpf(1.f + __expf(-v[0]));
          float act1 = fmaf(-2.f, __builtin_amdgcn_rcpf(1.f + __expf(2.f * v[1])), 1.f);
          float act2 = __builtin_amdgcn_rcpf(1.f + __expf(-v[2]));
          float act3 = fmaf(-2.f, __builtin_amdgcn_rcpf(1.f + __expf(2.f * v[3])), 1.f);
          ushort4 o;
          o.x = f2b(act0); o.y = f2b(act1); o.z = f2b(act2); o.w = f2b(act3);
          *(ushort4*)(outB + m * (long)N + nb) = o;
          // rounded values (== what pass3 will read back from P)
          const float fr0 = b2f(o.x), gr0 = b2f(o.y);
          const float fr1 = b2f(o.z), gr1 = b2f(o.w);
          float a0 = fr0, b0 = (1.f - fr0) * gr0;
          float a1 = fr1, b1 = (1.f - fr1) * gr1;
          BFLY16(a0, b0);
          BFLY16(a1, b1);
          if (hh == 0) {
            CA[j][0] = a0; CB[j][0] = b0;
            CA[j][1] = a1; CB[j][1] = b1;
          } else { // running(L) o window(R)
            CB[j][0] = fmaf(a0, CB[j][0], b0); CA[j][0] *= a0;
            CB[j][1] = fmaf(a1, CB[j][1], b1); CA[j][1] *= a1;
          }
        }
      }
      if (mloc == 0) {
        const int gchunk = (t0 >> 6) + cp; // 0..63
#pragma unroll
        for (int j = 0; j < 4; ++j) {
          const long ch0 = chb + j * 8 + kq4 * 2;
          const long i0 = (bIdx * CC + ch0) * 64 + gchunk;
          cA2[i0] = CA[j][0];       cB2[i0] = CB[j][0];
          cA2[i0 + 64] = CA[j][1];  cB2[i0 + 64] = CB[j][1];
        }
      }
    }
  }
}

// ===== Scan (R10): pass1 fused into gates epilogue; pass2 wave-parallel =====
// cA2/cB2/h2 layout: [chain][64] chain-major (coalesced per-wave access).
__global__ __launch_bounds__(256) void scan_pass2(const float* __restrict__ cA2,
                                                  const float* __restrict__ cB2,
                                                  float* __restrict__ h2) {
  const int gid = blockIdx.x * 256 + threadIdx.x;
  const int chain = gid >> 6; // one wave per chain (4096 chains)
  const int lane = threadIdx.x & 63;
  float Av = cA2[chain * 64 + lane];
  float Bv = cB2[chain * 64 + lane];
  // inclusive ordered scan over 64 chunk factors
#pragma unroll
  for (int m = 1; m < 64; m <<= 1) {
    const float Ao = __shfl_up(Av, m);
    const float Bo = __shfl_up(Bv, m);
    if (lane >= m) { Bv = fmaf(Av, Bo, Bv); Av = Av * Ao; }
  }
  // exclusive carry: h before chunk `lane`
  const float Bx = __shfl_up(Bv, 1);
  h2[chain * 64 + lane] = (lane == 0) ? 0.f : Bx;
}

// pass3: interleaved P ([m][2c]=f, [2c+1]=g) -> one 16B load per 4 channels.
__global__ __launch_bounds__(256) void scan_pass3(const ushort* __restrict__ P,
                                                  const float* __restrict__ h2,
                                                  ushort* __restrict__ H) {
  const int pc = blockIdx.x * 256 + threadIdx.x;
  const int chunk = blockIdx.y; // 0..63
  const int b = pc >> 8, c4 = (pc & 255) * 4;
  float h[4];
#pragma unroll
  for (int r = 0; r < 4; ++r) h[r] = h2[(b * CC + c4 + r) * 64 + chunk];
  const us8* p =
      (const us8*)(P + (size_t)(b * TT + chunk * CHUNK_T) * (2 * CC) + c4 * 2);
  ushort4* hp = (ushort4*)(H + (size_t)(b * TT + chunk * CHUNK_T) * CC + c4);
#pragma unroll 4
  for (int i = 0; i < CHUNK_T; ++i) {
    const us8 v = p[0];
    p += 2 * CC / 8;
    ushort4 o;
#pragma unroll
    for (int r = 0; r < 4; ++r) {
      const float f = b2f(v[2 * r]);
      const float g = b2f(v[2 * r + 1]);
      h[r] = fmaf(f, h[r], (1.f - f) * g);
    }
    o.x = f2b(h[0]); o.y = f2b(h[1]); o.z = f2b(h[2]); o.w = f2b(h[3]);
    *hp = o;
    hp += CC / 4;
  }
}

extern "C" void kernel_launch(void* const* d_in, const int* in_sizes, int n_in,
                              void* d_out, int out_size, void* d_ws, size_t ws_size,
                              hipStream_t stream) {
  const float* x  = (const float*)d_in[0];
  const float* Wf = (const float*)d_in[1];
  const float* Wg = (const float*)d_in[2];
  const float* Wp = (const float*)d_in[3];

  // workspace layout (bytes) -- identical footprint to R6-R9 (110,100,352 B).
  // H aliases xb (xb dead after gates GEMM, stream-ordered). cA2/cB2/h2 live
  // in the tail (written during gates epilogue -> must NOT overlay Wcat).
  char* ws = (char*)d_ws;
  ushort* xb   = (ushort*)(ws);                                  // 33554432 B
  ushort* Hb   = xb;                                             // alias
  ushort* Wcat = (ushort*)(ws + 33554432);                       //  4194304 B (interleaved Wf/Wg)
  ushort* Wpb  = (ushort*)(ws + 33554432 + 4194304);             //  2097152 B
  ushort* P    = (ushort*)(ws + 33554432 + 4194304 + 2097152);   // 67108864 B (f,g interleaved bf16)
  char* tail   = ws + 33554432 + 4194304 + 2097152 + 67108864;
  float* cA2   = (float*)(tail);                                 // 1 MiB (4096*64*4)
  float* cB2   = (float*)(tail + 1048576);                       // 1 MiB
  float* h2    = (float*)(tail + 2097152);                       // 1 MiB
  (void)ws_size; (void)in_sizes; (void)n_in; (void)out_size;

  // 1) all fp32 -> bf16 conversions in one launch (Wcat interleaved)
  cvt_all<<<19456, 256, 0, stream>>>(x, Wf, Wg, Wp, xb, Wcat, Wpb);

  // 2) gates GEMM + fused activation + chunk composition
  gemm_bt<1><<<512, 512, 0, stream>>>(xb, Wcat, nullptr, P, cA2, cB2, 2 * CC);

  // 3) carry scan (wave-parallel) + fixup sweep
  scan_pass2<<<NCHAIN * 64 / 256, 256, 0, stream>>>(cA2, cB2, h2);
  dim3 gs(NCHAIN / 4 / 256, NCHUNK);
  scan_pass3<<<gs, 256, 0, stream>>>(P, h2, Hb);

  // 4) projection GEMM: out = H @ Wp^T (fp32), 256x256 tiles -> 256 blocks
  gemm_bt<0><<<256, 512, 0, stream>>>(Hb, Wpb, (float*)d_out, nullptr, nullptr, nullptr, CC);
}

// Round 5
// 256.037 us; speedup vs baseline: 1.0962x; 1.0540x over previous
//
#include <hip/hip_runtime.h>
#include <hip/hip_bf16.h>
#include <stdint.h>

// Problem constants (B,T,C) = (4,4096,1024)
#define TT 4096
#define BB 4
#define CC 1024
#define MM (BB * TT)          // 16384 rows
#define NCHUNK 64             // scan chunks along T
#define CHUNK_T (TT / NCHUNK) // 64 steps per chunk
#define NCHAIN (BB * CC)      // 4096 independent scan chains

typedef float f32x4 __attribute__((ext_vector_type(4)));
typedef __bf16 bf16x8 __attribute__((ext_vector_type(8)));
typedef ushort us8 __attribute__((ext_vector_type(8)));

__device__ __forceinline__ float b2f(ushort u) {
  union { float f; uint32_t v; } x; x.v = ((uint32_t)u) << 16; return x.f;
}
__device__ __forceinline__ ushort f2b(float f) { // RNE fp32->bf16
  union { float f; uint32_t u; } x; x.f = f;
  uint32_t r = x.u + 0x7fffu + ((x.u >> 16) & 1u);
  return (ushort)(r >> 16);
}

// async global->LDS, 16B per lane. LDS dest must be uniform-base + lane*16.
__device__ __forceinline__ void async_copy16(const ushort* g, ushort* l) {
  __builtin_amdgcn_global_load_lds(
      (__attribute__((address_space(1))) void*)(g),
      (__attribute__((address_space(3))) void*)(l), 16, 0, 0);
}

// One kernel converts x, Wf, Wg, Wp to bf16. Sizes in float4 units:
// x: 4194304, each W: 262144. Total 4980736 = 19456 * 256 exactly.
// Wcat rows INTERLEAVED: row 2c = Wf[c], row 2c+1 = Wg[c], so the gates GEMM
// n-axis carries (f,g) channel pairs -> epilogue chunk-compose.
__global__ __launch_bounds__(256) void cvt_all(const float* __restrict__ x,
                                               const float* __restrict__ wf,
                                               const float* __restrict__ wg,
                                               const float* __restrict__ wp,
                                               ushort* __restrict__ xb,
                                               ushort* __restrict__ wcat,
                                               ushort* __restrict__ wpb) {
  const int i = blockIdx.x * 256 + threadIdx.x;
  const float* s; ushort* d; int off, dst;
  if (i < 4194304) {
    s = x; d = xb; off = i; dst = i;
  } else if (i < 4456448) {
    s = wf; d = wcat; off = i - 4194304;
    dst = ((off >> 8) << 9) + (off & 255);        // row c -> row 2c
  } else if (i < 4718592) {
    s = wg; d = wcat; off = i - 4456448;
    dst = ((off >> 8) << 9) + 256 + (off & 255);  // row c -> row 2c+1
  } else {
    s = wp; d = wpb; off = i - 4718592; dst = off;
  }
  float4 v = ((const float4*)s)[off];
  ushort4 o;
  o.x = f2b(v.x); o.y = f2b(v.y); o.z = f2b(v.z); o.w = f2b(v.w);
  ((ushort4*)d)[dst] = o;
}

// ===========================================================================
// GEMM core unchanged from R9/R10 (8-phase, 4-slot ring, counted vmcnt).
// ROUND-11: the MODE-1 fused chunk-compose epilogue is rebuilt. R10's
// 64x BFLY16 (512 ds_bpermute + ~800 VALU per thread, serial tail) cost
// +19 us on the gates dispatch (VALUBusy 22->30). New scheme: the 128 KB
// LDS ring is dead at the epilogue -> each wave gets a PRIVATE 16 KB slab
// [ch 32][slot 64] of (a,b) float2. Threads write their 32 pairs
// (ds_write_b64, slot = t ^ ch -> 4-cycle-minimum bank occupancy on both
// write and read), wave-local lgkmcnt(0), then lane=(ch, t-half) serially
// composes 32 steps and one ordered shfl_xor(32) merges halves. ~4x cheaper
// than the tree. Same rounded values, same t-order -> numerics unchanged.
// ===========================================================================

#define RDA(sl, ih)                                                       \
  _Pragma("unroll") for (int i_ = 0; i_ < 4; ++i_)                        \
      af[i_] = *(const bf16x8*)(rA + (sl) * 8192 + (ih) * 2048 + i_ * 512);

#define RDB(sl)                                                           \
  _Pragma("unroll") for (int j_ = 0; j_ < 4; ++j_)                        \
      bfr[j_] = *(const bf16x8*)(rB + (sl) * 8192 + j_ * 512);

#define MFMA16(ih)                                                        \
  __builtin_amdgcn_s_setprio(1);                                          \
  _Pragma("unroll") for (int i_ = 0; i_ < 4; ++i_)                        \
  _Pragma("unroll") for (int j_ = 0; j_ < 4; ++j_)                        \
      acc[(ih) * 4 + i_][j_] = __builtin_amdgcn_mfma_f32_16x16x32_bf16(   \
          bfr[j_], af[i_], acc[(ih) * 4 + i_][j_], 0, 0, 0);              \
  __builtin_amdgcn_s_setprio(0)

#define MIDBAR()                                                          \
  __builtin_amdgcn_s_barrier();                                           \
  asm volatile("s_waitcnt lgkmcnt(0)" ::: "memory");                      \
  __builtin_amdgcn_sched_barrier(0)

#define ENDBAR()                                                          \
  __builtin_amdgcn_s_barrier();                                           \
  __builtin_amdgcn_sched_barrier(0)

#define CK4() asm volatile("s_waitcnt vmcnt(4)" ::: "memory")
#define CK0() asm volatile("s_waitcnt vmcnt(0)" ::: "memory")

// One K-tile (BK=64) = 4 phases; stages the 4 pieces of the NEXT tile.
#define TILE(S0, S1, NS0, NS1, KN)                                        \
  RDA(S0, 0); RDB(S0); stageA(NS0, (KN));      MIDBAR(); MFMA16(0);        ENDBAR(); \
  RDA(S0, 1);          stageB(NS0, (KN));      MIDBAR(); MFMA16(1); CK4(); ENDBAR(); \
  RDA(S1, 0); RDB(S1); stageA(NS1, (KN) + 32); MIDBAR(); MFMA16(0);        ENDBAR(); \
  RDA(S1, 1);          stageB(NS1, (KN) + 32); MIDBAR(); MFMA16(1); CK4(); ENDBAR();

template <int MODE>
__global__ __launch_bounds__(512, 2) void gemm_bt(const ushort* __restrict__ A,
                                                  const ushort* __restrict__ Bw,
                                                  float* __restrict__ outF,
                                                  ushort* __restrict__ outB,
                                                  float* __restrict__ cA2,
                                                  float* __restrict__ cB2, int N) {
  constexpr int K = CC; // 1024 -> 16 K-tiles of 64 (32 K-half pieces)
  __shared__ __align__(16) ushort sA[4 * 256 * 32]; // 4 x 16 KB ring = 64 KB
  __shared__ __align__(16) ushort sB[4 * 256 * 32]; // 64 KB

  const int tid = threadIdx.x;
  const int lane = tid & 63;
  const int w = tid >> 6;  // 0..7
  const int wm = w >> 2;   // 0..1: 128-row M half
  const int wn = w & 3;    // 0..3: 64-col N quarter

  // XCD-aware bijective swizzle (nwg = 512 or 256, both % 8 == 0)
  const int nbx = N >> 8;
  const int cpx = (int)gridDim.x >> 3;
  const int bid = blockIdx.x;
  const int wg = (bid & 7) * cpx + (bid >> 3);
  const long n0 = (long)(wg % nbx) << 8;
  const long m0 = (long)(wg / nbx) << 8;

  // ---- staging: piece = 256 rows x 64 B. Wave w covers rows w*16..+15 (hb0)
  // and 128+w*16..+15 (hb1), one gload_lds (1 KB) each. lane -> row lane>>2,
  // LDS octet lane&3; global octet pre-swizzled (lane&3)^((lane>>3)&3).
  const int srow = lane >> 2;
  const int goct = (lane & 3) ^ ((lane >> 3) & 3);
  const ushort* gA0 = A + (m0 + w * 16 + srow) * K + goct * 8;
  const ushort* gB0 = Bw + (n0 + w * 16 + srow) * K + goct * 8;
  const ushort* gA1 = gA0 + 128 * (long)K;
  const ushort* gB1 = gB0 + 128 * (long)K;
  ushort* dA0 = &sA[w * 512 + lane * 8];
  ushort* dA1 = dA0 + 4096; // rows +128 within piece
  ushort* dB0 = &sB[w * 512 + lane * 8];
  ushort* dB1 = dB0 + 4096;

  auto stageA = [&](int slot, int koff) {
    async_copy16(gA0 + koff, dA0 + slot * 8192);
    async_copy16(gA1 + koff, dA1 + slot * 8192);
  };
  auto stageB = [&](int slot, int koff) {
    async_copy16(gB0 + koff, dB0 + slot * 8192);
    async_copy16(gB1 + koff, dB1 + slot * 8192);
  };

  // ---- fragment reads: row r, octet slot kq ^ ((r>>1)&3)  (R7 0-conflict)
  const int rlo = lane & 15;
  const int kq = lane >> 4;
  const int oslot = kq ^ ((rlo >> 1) & 3);
  const ushort* rA = &sA[(wm * 128 + rlo) * 32 + oslot * 8]; // +sl*8192+ih*2048+i*512
  const ushort* rB = &sB[(wn * 64 + rlo) * 32 + oslot * 8];  // +sl*8192+j*512

  f32x4 acc[8][4];
#pragma unroll
  for (int i = 0; i < 8; ++i)
#pragma unroll
    for (int j = 0; j < 4; ++j) acc[i][j] = (f32x4){0.f, 0.f, 0.f, 0.f};

  bf16x8 af[4], bfr[4];

  // prologue: stage tile 0's 4 pieces; confirm As0,Bs0 (leave As1,Bs1 flying)
  stageA(0, 0);
  stageB(0, 0);
  stageA(1, 32);
  stageB(1, 32);
  CK4();
  ENDBAR();

  // main loop: tiles 0..13 (2 per iter; slot pattern period 2 -> constants)
  for (int t2 = 0; t2 < 7; ++t2) {
    const int kn = t2 * 128 + 64; // stage koff for tile 2*t2+1
    TILE(0, 1, 2, 3, kn);         // even tile: reads slots 0,1; stages 2,3
    TILE(2, 3, 0, 1, kn + 64);    // odd tile:  reads slots 2,3; stages 0,1
  }
  // tile 14 (even): stages tile 15 (slots 2,3; koff 960/992)
  TILE(0, 1, 2, 3, 960);
  // tile 15 (odd, slots 2,3): no stages; drain only here
  RDA(2, 0); RDB(2); MIDBAR(); MFMA16(0); ENDBAR();
  RDA(2, 1);         MIDBAR(); MFMA16(1); CK0(); ENDBAR();
  RDA(3, 0); RDB(3); MIDBAR(); MFMA16(0); ENDBAR();
  RDA(3, 1);         MIDBAR(); MFMA16(1);

  // Swapped C/D mapping (R3-verified): m = lane&15 axis, n = (lane>>4)*4 + reg.
  const int mloc = lane & 15;
  const int nq = (lane >> 4) * 4;

  if (MODE == 0) {
#pragma unroll
    for (int i = 0; i < 8; ++i) {
      const long m = m0 + wm * 128 + i * 16 + mloc;
#pragma unroll
      for (int j = 0; j < 4; ++j) {
        const long nb = n0 + wn * 64 + j * 16 + nq;
        *(f32x4*)(outF + m * N + nb) = acc[i][j];
      }
    }
  } else {
    // ---- fused activation + P store + chunk compose (LDS-slab version) ----
    const long bIdx = m0 >> 12;                   // batch
    const int t0 = (int)(m0 & 4095) + wm * 128;   // wave t base (mult of 128)
    const long chb = (n0 >> 1) + wn * 32;         // wave channel base
    // per-wave PRIVATE 16 KB slab: waves 0-3 carve sA, waves 4-7 carve sB.
    float* slab = (float*)((w < 4) ? &sA[w * 8192] : &sB[(w - 4) * 8192]);
    // one block barrier: every wave's GEMM ds_reads are lgkm-drained before
    // its last MFMA, so after this barrier the ring is safely reusable.
    __builtin_amdgcn_s_barrier();
    __builtin_amdgcn_sched_barrier(0);

    const int chl = lane & 31;  // read-phase: local channel
    const int thf = lane >> 5;  // read-phase: t-half of the 64-t chunk
#pragma unroll
    for (int rd = 0; rd < 2; ++rd) {              // i-halves = 64-t chunks
      // write phase: 4 i x 4 j frags x 2 ch-pairs = 32 float2 stores
#pragma unroll
      for (int ii = 0; ii < 4; ++ii) {
        const int i = rd * 4 + ii;
        const long m = m0 + wm * 128 + i * 16 + mloc;
        const int tl = ii * 16 + mloc;            // t within chunk, 0..63
#pragma unroll
        for (int j = 0; j < 4; ++j) {
          const long nb = n0 + wn * 64 + j * 16 + nq;
          const f32x4 v = acc[i][j];
          // parity activation: even n = f (sigmoid), odd n = g (tanh)
          float f0 = __builtin_amdgcn_rcpf(1.f + __expf(-v[0]));
          float g0 = fmaf(-2.f, __builtin_amdgcn_rcpf(1.f + __expf(2.f * v[1])), 1.f);
          float f1 = __builtin_amdgcn_rcpf(1.f + __expf(-v[2]));
          float g1 = fmaf(-2.f, __builtin_amdgcn_rcpf(1.f + __expf(2.f * v[3])), 1.f);
          ushort4 o;
          o.x = f2b(f0); o.y = f2b(g0); o.z = f2b(f1); o.w = f2b(g1);
          *(ushort4*)(outB + m * (long)N + nb) = o;
          // rounded values (== what pass3 reads back from P)
          const float fr0 = b2f(o.x), gr0 = b2f(o.y);
          const float fr1 = b2f(o.z), gr1 = b2f(o.w);
          const int c0 = j * 8 + (nq >> 1);       // local ch of (v0,v1)
          float2 p0; p0.x = fr0; p0.y = (1.f - fr0) * gr0;
          float2 p1; p1.x = fr1; p1.y = (1.f - fr1) * gr1;
          // slab[ch][slot] with slot = t ^ ch (bank-spread involution)
          *(float2*)(slab + (c0 * 64 + (tl ^ c0)) * 2) = p0;
          *(float2*)(slab + ((c0 + 1) * 64 + (tl ^ (c0 + 1))) * 2) = p1;
        }
      }
      // wave-private slab -> wave-local wait only (no block barrier)
      asm volatile("s_waitcnt lgkmcnt(0)" ::: "memory");
      __builtin_amdgcn_sched_barrier(0);
      // read+compose: lane = (ch=chl, t-half=thf), 32 ordered serial steps
      float Av = 1.f, Bv = 0.f;
#pragma unroll
      for (int s = 0; s < 32; ++s) {
        const int t = thf * 32 + s;
        const float2 ab = *(const float2*)(slab + (chl * 64 + (t ^ chl)) * 2);
        Bv = fmaf(ab.x, Bv, ab.y);
        Av *= ab.x;
      }
      // ordered merge across t-halves: full = hi o lo
      const float Ao = __shfl_xor(Av, 32);
      const float Bo = __shfl_xor(Bv, 32);
      const float Af = (thf == 0) ? Ao * Av : Av * Ao;
      const float Bf = (thf == 0) ? fmaf(Ao, Bv, Bo) : fmaf(Av, Bo, Bv);
      if (thf == 0) {
        const int gchunk = (t0 >> 6) + rd;        // 0..63
        const long i0 = (bIdx * CC + chb + chl) * 64 + gchunk;
        cA2[i0] = Af;
        cB2[i0] = Bf;
      }
      if (rd == 0) { // reads done before next round overwrites the slab
        asm volatile("s_waitcnt lgkmcnt(0)" ::: "memory");
        __builtin_amdgcn_sched_barrier(0);
      }
    }
  }
}

// ===== Scan: pass1 fused into gates epilogue; pass2 wave-parallel =====
// cA2/cB2/h2 layout: [chain][64] chain-major (coalesced per-wave access).
__global__ __launch_bounds__(256) void scan_pass2(const float* __restrict__ cA2,
                                                  const float* __restrict__ cB2,
                                                  float* __restrict__ h2) {
  const int gid = blockIdx.x * 256 + threadIdx.x;
  const int chain = gid >> 6; // one wave per chain (4096 chains)
  const int lane = threadIdx.x & 63;
  float Av = cA2[chain * 64 + lane];
  float Bv = cB2[chain * 64 + lane];
  // inclusive ordered scan over 64 chunk factors
#pragma unroll
  for (int m = 1; m < 64; m <<= 1) {
    const float Ao = __shfl_up(Av, m);
    const float Bo = __shfl_up(Bv, m);
    if (lane >= m) { Bv = fmaf(Av, Bo, Bv); Av = Av * Ao; }
  }
  // exclusive carry: h before chunk `lane`
  const float Bx = __shfl_up(Bv, 1);
  h2[chain * 64 + lane] = (lane == 0) ? 0.f : Bx;
}

// pass3: interleaved P ([m][2c]=f, [2c+1]=g) -> one 16B load per 4 channels.
__global__ __launch_bounds__(256) void scan_pass3(const ushort* __restrict__ P,
                                                  const float* __restrict__ h2,
                                                  ushort* __restrict__ H) {
  const int pc = blockIdx.x * 256 + threadIdx.x;
  const int chunk = blockIdx.y; // 0..63
  const int b = pc >> 8, c4 = (pc & 255) * 4;
  float h[4];
#pragma unroll
  for (int r = 0; r < 4; ++r) h[r] = h2[(b * CC + c4 + r) * 64 + chunk];
  const us8* p =
      (const us8*)(P + (size_t)(b * TT + chunk * CHUNK_T) * (2 * CC) + c4 * 2);
  ushort4* hp = (ushort4*)(H + (size_t)(b * TT + chunk * CHUNK_T) * CC + c4);
#pragma unroll 4
  for (int i = 0; i < CHUNK_T; ++i) {
    const us8 v = p[0];
    p += 2 * CC / 8;
    ushort4 o;
#pragma unroll
    for (int r = 0; r < 4; ++r) {
      const float f = b2f(v[2 * r]);
      const float g = b2f(v[2 * r + 1]);
      h[r] = fmaf(f, h[r], (1.f - f) * g);
    }
    o.x = f2b(h[0]); o.y = f2b(h[1]); o.z = f2b(h[2]); o.w = f2b(h[3]);
    *hp = o;
    hp += CC / 4;
  }
}

extern "C" void kernel_launch(void* const* d_in, const int* in_sizes, int n_in,
                              void* d_out, int out_size, void* d_ws, size_t ws_size,
                              hipStream_t stream) {
  const float* x  = (const float*)d_in[0];
  const float* Wf = (const float*)d_in[1];
  const float* Wg = (const float*)d_in[2];
  const float* Wp = (const float*)d_in[3];

  // workspace layout (bytes) -- identical footprint to R6-R10.
  // H aliases xb (xb dead after gates GEMM, stream-ordered). cA2/cB2/h2 live
  // in the tail (written during gates epilogue -> must NOT overlay Wcat).
  char* ws = (char*)d_ws;
  ushort* xb   = (ushort*)(ws);                                  // 33554432 B
  ushort* Hb   = xb;                                             // alias
  ushort* Wcat = (ushort*)(ws + 33554432);                       //  4194304 B (interleaved Wf/Wg)
  ushort* Wpb  = (ushort*)(ws + 33554432 + 4194304);             //  2097152 B
  ushort* P    = (ushort*)(ws + 33554432 + 4194304 + 2097152);   // 67108864 B (f,g interleaved bf16)
  char* tail   = ws + 33554432 + 4194304 + 2097152 + 67108864;
  float* cA2   = (float*)(tail);                                 // 1 MiB (4096*64*4)
  float* cB2   = (float*)(tail + 1048576);                       // 1 MiB
  float* h2    = (float*)(tail + 2097152);                       // 1 MiB
  (void)ws_size; (void)in_sizes; (void)n_in; (void)out_size;

  // 1) all fp32 -> bf16 conversions in one launch (Wcat interleaved)
  cvt_all<<<19456, 256, 0, stream>>>(x, Wf, Wg, Wp, xb, Wcat, Wpb);

  // 2) gates GEMM + fused activation + chunk composition
  gemm_bt<1><<<512, 512, 0, stream>>>(xb, Wcat, nullptr, P, cA2, cB2, 2 * CC);

  // 3) carry scan (wave-parallel) + fixup sweep
  scan_pass2<<<NCHAIN * 64 / 256, 256, 0, stream>>>(cA2, cB2, h2);
  dim3 gs(NCHAIN / 4 / 256, NCHUNK);
  scan_pass3<<<gs, 256, 0, stream>>>(P, h2, Hb);

  // 4) projection GEMM: out = H @ Wp^T (fp32), 256x256 tiles -> 256 blocks
  gemm_bt<0><<<256, 512, 0, stream>>>(Hb, Wpb, (float*)d_out, nullptr, nullptr, nullptr, CC);
}